// Round 1
// baseline (148.723 us; speedup 1.0000x reference)
//
#include <hip/hip_runtime.h>

// Problem constants
#define BB 8
#define HWSZ 65536            // 256*256
#define PLANE (3 * HWSZ)      // one batch's [3,H,W]
#define OUTSTRIDE (BB * PLANE) // one full output tensor [8,3,256,256]

// ---------------------------------------------------------------------------
// Stage 1: four stacked projections, fc1: h[k,b,o] = relu(feat[k,b] . w1[k,:,o] + b1[k,o])
// grid 32 = (k*8+b), block 192 = o
__global__ __launch_bounds__(192) void k_proj1(
    const float* __restrict__ f, const float* __restrict__ bf,
    const float* __restrict__ w1, const float* __restrict__ b1,
    float* __restrict__ h) {
  int k = blockIdx.x >> 3, b = blockIdx.x & 7, o = threadIdx.x;
  __shared__ float sf[512];
  const float* feat = (k & 1) ? (bf + b * 512) : (f + b * 512);
  for (int i = o; i < 512; i += 192) sf[i] = feat[i];
  __syncthreads();
  const float* w = w1 + (size_t)k * (512 * 192) + o;
  float acc = b1[k * 192 + o];
#pragma unroll 8
  for (int i = 0; i < 512; ++i) acc = fmaf(sf[i], w[(size_t)i * 192], acc);
  h[(k * 8 + b) * 192 + o] = fmaxf(acc, 0.f);
}

// Stage 2: outs[k,b,o] = h[k,b] . w2[k,:,o] + b2[k,o]
__global__ __launch_bounds__(192) void k_proj2(
    const float* __restrict__ h, const float* __restrict__ w2,
    const float* __restrict__ b2, float* __restrict__ outs) {
  int k = blockIdx.x >> 3, b = blockIdx.x & 7, o = threadIdx.x;
  __shared__ float sh[192];
  sh[o] = h[(k * 8 + b) * 192 + o];
  __syncthreads();
  const float* w = w2 + (size_t)k * (192 * 192) + o;
  float acc = b2[k * 192 + o];
#pragma unroll 8
  for (int i = 0; i < 192; ++i) acc = fmaf(sh[i], w[(size_t)i * 192], acc);
  outs[(k * 8 + b) * 192 + o] = acc;
}

// Stage 3: cat = [outs0[b], outs1[b], outs2[b]+outs3[b]] (576); hcat = relu(cat.W1 + b1)
// grid 8 = b, block 192 = o
__global__ __launch_bounds__(192) void k_fcat1(
    const float* __restrict__ outs, const float* __restrict__ w1,
    const float* __restrict__ bias, float* __restrict__ hcat) {
  int b = blockIdx.x, o = threadIdx.x;
  __shared__ float sc[576];
  sc[o]       = outs[(0 * 8 + b) * 192 + o];
  sc[192 + o] = outs[(1 * 8 + b) * 192 + o];
  sc[384 + o] = outs[(2 * 8 + b) * 192 + o] + outs[(3 * 8 + b) * 192 + o];
  __syncthreads();
  const float* w = w1 + o;
  float acc = bias[o];
#pragma unroll 8
  for (int i = 0; i < 576; ++i) acc = fmaf(sc[i], w[(size_t)i * 192], acc);
  hcat[b * 192 + o] = fmaxf(acc, 0.f);
}

// Stage 4: param[b,o] = hcat[b] . W2[:,o] + b2[o]
__global__ __launch_bounds__(192) void k_fcat2(
    const float* __restrict__ hcat, const float* __restrict__ w2,
    const float* __restrict__ bias, float* __restrict__ param) {
  int b = blockIdx.x, o = threadIdx.x;
  __shared__ float sh[192];
  sh[o] = hcat[b * 192 + o];
  __syncthreads();
  const float* w = w2 + o;
  float acc = bias[o];
#pragma unroll 8
  for (int i = 0; i < 192; ++i) acc = fmaf(sh[i], w[(size_t)i * 192], acc);
  param[b * 192 + o] = acc;
}

// ---------------------------------------------------------------------------
// Render: closed-form piecewise-linear curve eval.
// total(v) = S_k/64 + (v - k/64) * p_k,  k = floor(64 v);  out = total * 64/(S_64+eps)
// Curves: cur = oi*3 + c; oi=0 -> p_all (param), oi=1 -> p_f (outs[0]), oi=2 -> p_b (outs[1])
__global__ __launch_bounds__(256) void k_render(
    const float* __restrict__ x, const float* __restrict__ p_all,
    const float* __restrict__ outs, float* __restrict__ out) {
  int b = blockIdx.y, tid = threadIdx.x;
  __shared__ float sp[9][64];
  __shared__ float sS[9][65];
  __shared__ float snorm[9];

  for (int idx = tid; idx < 576; idx += 256) {
    int cur = idx >> 6, i = idx & 63;
    int oi = cur / 3, c = cur - oi * 3;
    sp[cur][i] = (oi == 0) ? p_all[b * 192 + c * 64 + i]
                           : outs[((oi - 1) * 8 + b) * 192 + c * 64 + i];
  }
  __syncthreads();
  if (tid < 9) {
    float s = 0.f;
    sS[tid][0] = 0.f;
    for (int i = 0; i < 64; ++i) { s += sp[tid][i]; sS[tid][i + 1] = s; }
    snorm[tid] = 64.f / (s + 1e-30f);
  }
  __syncthreads();

  auto ev = [&](int cur, float v) -> float {
    int k = (int)(v * 64.f);
    k = k < 0 ? 0 : (k > 63 ? 63 : k);
    float t = v - (float)k * 0.015625f;
    return fmaf(sS[cur][k], 0.015625f, t * sp[cur][k]) * snorm[cur];
  };
  auto ev4 = [&](int cur, float4 v) -> float4 {
    float4 r;
    r.x = ev(cur, v.x); r.y = ev(cur, v.y);
    r.z = ev(cur, v.z); r.w = ev(cur, v.w);
    return r;
  };

  int s4 = blockIdx.x * 256 + tid;  // float4 index within one channel plane (16384 total)
  const float* xb = x + (size_t)b * PLANE;
  float4 vr = ((const float4*)(xb))[s4];
  float4 vg = ((const float4*)(xb + HWSZ))[s4];
  float4 vb = ((const float4*)(xb + 2 * HWSZ))[s4];

  float4 gr;
  gr.x = fmaf(0.299f, vr.x, fmaf(0.587f, vg.x, 0.114f * vb.x));
  gr.y = fmaf(0.299f, vr.y, fmaf(0.587f, vg.y, 0.114f * vb.y));
  gr.z = fmaf(0.299f, vr.z, fmaf(0.587f, vg.z, 0.114f * vb.z));
  gr.w = fmaf(0.299f, vr.w, fmaf(0.587f, vg.w, 0.114f * vb.w));

  float* o0 = out + (size_t)b * PLANE;                 // cf(x, p_all)
  float* o1 = out + OUTSTRIDE + (size_t)b * PLANE;     // cf(gray, p_f)
  float* o2 = out + 2 * OUTSTRIDE + (size_t)b * PLANE; // cf(gray, p_b)

  ((float4*)(o0))[s4]             = ev4(0, vr);
  ((float4*)(o0 + HWSZ))[s4]      = ev4(1, vg);
  ((float4*)(o0 + 2 * HWSZ))[s4]  = ev4(2, vb);
  ((float4*)(o1))[s4]             = ev4(3, gr);
  ((float4*)(o1 + HWSZ))[s4]      = ev4(4, gr);
  ((float4*)(o1 + 2 * HWSZ))[s4]  = ev4(5, gr);
  ((float4*)(o2))[s4]             = ev4(6, gr);
  ((float4*)(o2 + HWSZ))[s4]      = ev4(7, gr);
  ((float4*)(o2 + 2 * HWSZ))[s4]  = ev4(8, gr);
}

// ---------------------------------------------------------------------------
extern "C" void kernel_launch(void* const* d_in, const int* in_sizes, int n_in,
                              void* d_out, int out_size, void* d_ws, size_t ws_size,
                              hipStream_t stream) {
  const float* x   = (const float*)d_in[0];
  const float* f   = (const float*)d_in[1];
  const float* bf  = (const float*)d_in[2];
  const float* pw1 = (const float*)d_in[3];
  const float* pb1 = (const float*)d_in[4];
  const float* pw2 = (const float*)d_in[5];
  const float* pb2 = (const float*)d_in[6];
  const float* fw1 = (const float*)d_in[7];
  const float* fb1 = (const float*)d_in[8];
  const float* fw2 = (const float*)d_in[9];
  const float* fb2 = (const float*)d_in[10];
  float* out = (float*)d_out;
  float* ws  = (float*)d_ws;

  float* h     = ws;          // [4,8,192] = 6144
  float* outs  = ws + 6144;   // [4,8,192] = 6144
  float* hcat  = ws + 12288;  // [8,192]   = 1536
  float* param = ws + 13824;  // [8,192]   = 1536

  k_proj1<<<32, 192, 0, stream>>>(f, bf, pw1, pb1, h);
  k_proj2<<<32, 192, 0, stream>>>(h, pw2, pb2, outs);
  k_fcat1<<<8, 192, 0, stream>>>(outs, fw1, fb1, hcat);
  k_fcat2<<<8, 192, 0, stream>>>(hcat, fw2, fb2, param);
  dim3 grid(64, 8);
  k_render<<<grid, 256, 0, stream>>>(x, param, outs, out);
}